// Round 4
// baseline (41.818 us; speedup 1.0000x reference)
//
#include <hip/hip_runtime.h>
#include <math.h>

constexpr int IMG = 224;
constexpr int Bb  = 16;
constexpr int Vv  = 8;
constexpr int Nn  = 8192;
constexpr int Mm  = 1024;

typedef float sf8 __attribute__((ext_vector_type(8)));

// ---------- Kernel A: normalize bounds -> planar ws arrays ----------------
// ws layout: wsx[16][1024] | wsy[16][1024] | wsn[16][1024]  (192 KiB)
__global__ __launch_bounds__(256) void prep_kernel(
    const float* __restrict__ bounds, const int* __restrict__ view_p,
    float* __restrict__ ws)
{
    const int view = *view_p;
    const int b = blockIdx.x;
    const float* bnd = bounds + (size_t)(b * Vv + view) * Mm * 2;
    float* wsx = ws;
    float* wsy = ws + Bb * Mm;
    float* wsn = ws + 2 * Bb * Mm;
    for (int j = threadIdx.x; j < Mm; j += 256) {
        float2 bxy = reinterpret_cast<const float2*>(bnd)[j];
        float bdx = bxy.x / (float)IMG;   // exact IEEE div, matches ref
        float bdy = bxy.y / (float)IMG;
        float nrm = __fadd_rn(__fmul_rn(bdx, bdx), __fmul_rn(bdy, bdy));
        wsx[b * Mm + j] = bdx;
        wsy[b * Mm + j] = bdy;
        wsn[b * Mm + j] = nrm;
    }
}

// ---------- Kernel B: scalar-operand, branch-free NN scan -----------------
// Block = 256 threads = 4 waves; 64 points per block (lane = point);
// wave w scans candidate slice [256w, 256w+256), candidates in SGPRs.
__global__ __launch_bounds__(256) void calib_kernel(
    const float* __restrict__ pc,         // (B, N, 3)
    const float* __restrict__ mask,       // (B, V, IMG, IMG)
    const float* __restrict__ bounds,     // (B, V, M, 2)
    const float* __restrict__ inv_param,  // (B, V, 4, 4)
    const float* __restrict__ proj_fine,  // (B, V, N, 2)
    const float* __restrict__ proj_finez, // (B, V, N)
    const int*   __restrict__ view_p,     // scalar
    const float* __restrict__ ws,         // normalized candidates (planar)
    float*       __restrict__ out)        // (B, N, 3)
{
    const int view = *view_p;
    const int b = blockIdx.y;
    const int l = threadIdx.x & 63;
    const int wu = __builtin_amdgcn_readfirstlane(threadIdx.x >> 6);
    const int i = blockIdx.x * 64 + l;

    const size_t pf = (size_t)(b * Vv + view) * Nn + i;
    float2 pxy = reinterpret_cast<const float2*>(proj_fine)[pf];

    int i0 = (int)rintf(pxy.x);                 // round half-to-even
    int i1 = (int)rintf((float)IMG - pxy.y);

    float ox = (float)i0 / (float)IMG;
    float oy = (float)i1 / (float)IMG;
    float o2 = __fadd_rn(__fmul_rn(ox, ox), __fmul_rn(oy, oy));
    // exact power-of-2 scale; d2 bits identical to ref association
    float n2ox = __fmul_rn(-2.0f, ox);
    float n2oy = __fmul_rn(-2.0f, oy);

    const float* wx = ws + (size_t)b * Mm + wu * 256;
    const float* wy = wx + Bb * Mm;
    const float* wn = wx + 2 * Bb * Mm;
    const int jbase = wu * 256;

    float best = INFINITY;
    int   bj   = 0;
    for (int q = 0; q < 16; ++q) {
        sf8 X0, X1, Y0, Y1, Z0, Z1;
        const float* px0 = wx + 16 * q;
        const float* py0 = wy + 16 * q;
        const float* pz0 = wn + 16 * q;
        asm volatile("s_load_dwordx8 %0, %1, 0x0" : "=s"(X0) : "s"(px0));
        asm volatile("s_load_dwordx8 %0, %1, 0x0" : "=s"(X1) : "s"(px0 + 8));
        asm volatile("s_load_dwordx8 %0, %1, 0x0" : "=s"(Y0) : "s"(py0));
        asm volatile("s_load_dwordx8 %0, %1, 0x0" : "=s"(Y1) : "s"(py0 + 8));
        asm volatile("s_load_dwordx8 %0, %1, 0x0" : "=s"(Z0) : "s"(pz0));
        asm volatile("s_load_dwordx8 %0, %1, 0x0" : "=s"(Z1) : "s"(pz0 + 8));
        // consumers data-depend on the waitcnt's outputs -> cannot be hoisted
        asm volatile("s_waitcnt lgkmcnt(0)"
                     : "+s"(X0), "+s"(X1), "+s"(Y0), "+s"(Y1), "+s"(Z0), "+s"(Z1));
        #pragma unroll
        for (int k = 0; k < 8; ++k) {
            {
                float dn = __fadd_rn(__fmul_rn(n2ox, X0[k]), __fmul_rn(n2oy, Y0[k]));
                float d2 = __fadd_rn(__fadd_rn(o2, Z0[k]), dn);
                int   j  = jbase + 16 * q + k;
                bool  c  = d2 < best;          // strict < = first-index ties
                bj   = c ? j  : bj;            // v_cndmask (j uniform SGPR)
                best = fminf(best, d2);        // v_min_f32, no vcc dep
            }
            {
                float dn = __fadd_rn(__fmul_rn(n2ox, X1[k]), __fmul_rn(n2oy, Y1[k]));
                float d2 = __fadd_rn(__fadd_rn(o2, Z1[k]), dn);
                int   j  = jbase + 16 * q + 8 + k;
                bool  c  = d2 < best;
                bj   = c ? j  : bj;
                best = fminf(best, d2);
            }
        }
    }

    // ---- merge the 4 wave slices (lexicographic: d2, then smaller j) ----
    __shared__ float s_best[4][64];
    __shared__ int   s_bj[4][64];
    s_best[wu][l] = best;
    s_bj[wu][l]   = bj;
    __syncthreads();

    if (threadIdx.x < 64) {
        float bestm = s_best[0][l];
        int   bjm   = s_bj[0][l];
        #pragma unroll
        for (int w = 1; w < 4; ++w) {
            float bw = s_best[w][l];
            int   jw = s_bj[w][l];
            bool  c  = (bw < bestm) || (bw == bestm && jw < bjm);
            bestm = c ? bw : bestm;
            bjm   = c ? jw : bjm;
        }

        // padded-mask probe
        int xi = min(max(i1 + 1, 0), IMG + 1);
        int yi = min(max(i0 + 1, 0), IMG + 1);
        float mval = 0.0f;
        if (xi >= 1 && xi <= IMG && yi >= 1 && yi <= IMG)
            mval = mask[((size_t)(b * Vv + view) * IMG + (xi - 1)) * IMG + (yi - 1)];
        const bool use_back = (mval == 0.0f);

        // back-projection: [nbx*z, nby*z, z, 1] @ inv_param[b, view][:, 0:3]
        const float* bnd = bounds + (size_t)(b * Vv + view) * Mm * 2;
        float nbx = bnd[2 * bjm];
        float nby = bnd[2 * bjm + 1];
        float z   = proj_finez[pf];
        const float* ip = inv_param + (size_t)(b * Vv + view) * 16;
        float h0 = nbx * z, h1 = nby * z;
        float r0 = h0 * ip[0] + h1 * ip[4] + z * ip[8]  + ip[12];
        float r1 = h0 * ip[1] + h1 * ip[5] + z * ip[9]  + ip[13];
        float r2 = h0 * ip[2] + h1 * ip[6] + z * ip[10] + ip[14];

        const size_t ob = ((size_t)b * Nn + i) * 3;
        float c0 = pc[ob], c1 = pc[ob + 1], c2 = pc[ob + 2];
        out[ob]     = use_back ? r0 : c0;
        out[ob + 1] = use_back ? r1 : c1;
        out[ob + 2] = use_back ? r2 : c2;
    }
}

// ---------- Fallback (R2 kernel) if ws is too small -----------------------
__global__ __launch_bounds__(256) void calib_fallback(
    const float* __restrict__ pc, const float* __restrict__ mask,
    const float* __restrict__ bounds, const float* __restrict__ inv_param,
    const float* __restrict__ proj_fine, const float* __restrict__ proj_finez,
    const int* __restrict__ view_p, float* __restrict__ out)
{
    const int view = *view_p;
    const int b = blockIdx.y;
    const int s = threadIdx.x & 3;
    const int p_local = threadIdx.x >> 2;
    const int i = blockIdx.x * 64 + p_local;

    __shared__ float4 s_bd[Mm];
    const float* bnd = bounds + (size_t)(b * Vv + view) * Mm * 2;
    for (int j = threadIdx.x; j < Mm; j += 256) {
        float2 bxy = reinterpret_cast<const float2*>(bnd)[j];
        float bdx = bxy.x / (float)IMG;
        float bdy = bxy.y / (float)IMG;
        float nrm = __fadd_rn(__fmul_rn(bdx, bdx), __fmul_rn(bdy, bdy));
        s_bd[j] = make_float4(bdx, bdy, nrm, 0.0f);
    }
    __syncthreads();

    const size_t pf = (size_t)(b * Vv + view) * Nn + i;
    float2 pxy = reinterpret_cast<const float2*>(proj_fine)[pf];
    int i0 = (int)rintf(pxy.x);
    int i1 = (int)rintf((float)IMG - pxy.y);
    float ox = (float)i0 / (float)IMG;
    float oy = (float)i1 / (float)IMG;
    float o2 = __fadd_rn(__fmul_rn(ox, ox), __fmul_rn(oy, oy));
    float n2ox = __fmul_rn(-2.0f, ox);
    float n2oy = __fmul_rn(-2.0f, oy);

    float best = INFINITY;
    int bj = 0;
    const float4* sp = s_bd + s;
    #pragma unroll 4
    for (int q = 0; q < Mm / 4; ++q) {
        float4 bd = sp[4 * q];
        int j = 4 * q + s;
        float dn = __fadd_rn(__fmul_rn(n2ox, bd.x), __fmul_rn(n2oy, bd.y));
        float d2 = __fadd_rn(__fadd_rn(o2, bd.z), dn);
        bool c = d2 < best;
        bj = c ? j : bj;
        best = fminf(best, d2);
    }
    #pragma unroll
    for (int off = 1; off < 4; off <<= 1) {
        float bo = __shfl_xor(best, off);
        int   jo = __shfl_xor(bj, off);
        bool  c  = (bo < best) || (bo == best && jo < bj);
        best = c ? bo : best;
        bj   = c ? jo : bj;
    }
    if (s == 0) {
        int xi = min(max(i1 + 1, 0), IMG + 1);
        int yi = min(max(i0 + 1, 0), IMG + 1);
        float mval = 0.0f;
        if (xi >= 1 && xi <= IMG && yi >= 1 && yi <= IMG)
            mval = mask[((size_t)(b * Vv + view) * IMG + (xi - 1)) * IMG + (yi - 1)];
        const bool use_back = (mval == 0.0f);
        float nbx = bnd[2 * bj];
        float nby = bnd[2 * bj + 1];
        float z   = proj_finez[pf];
        const float* ip = inv_param + (size_t)(b * Vv + view) * 16;
        float h0 = nbx * z, h1 = nby * z;
        float r0 = h0 * ip[0] + h1 * ip[4] + z * ip[8]  + ip[12];
        float r1 = h0 * ip[1] + h1 * ip[5] + z * ip[9]  + ip[13];
        float r2 = h0 * ip[2] + h1 * ip[6] + z * ip[10] + ip[14];
        const size_t ob = ((size_t)b * Nn + i) * 3;
        float c0 = pc[ob], c1 = pc[ob + 1], c2 = pc[ob + 2];
        out[ob]     = use_back ? r0 : c0;
        out[ob + 1] = use_back ? r1 : c1;
        out[ob + 2] = use_back ? r2 : c2;
    }
}

extern "C" void kernel_launch(void* const* d_in, const int* in_sizes, int n_in,
                              void* d_out, int out_size, void* d_ws, size_t ws_size,
                              hipStream_t stream) {
    const float* pc         = (const float*)d_in[0];
    const float* mask       = (const float*)d_in[1];
    const float* bounds     = (const float*)d_in[2];
    const float* inv_param  = (const float*)d_in[3];
    const float* proj_fine  = (const float*)d_in[4];
    const float* proj_finez = (const float*)d_in[5];
    const int*   view_p     = (const int*)d_in[6];
    float* out = (float*)d_out;

    const size_t ws_need = (size_t)3 * Bb * Mm * sizeof(float);  // 192 KiB
    if (ws_size >= ws_need) {
        float* ws = (float*)d_ws;
        prep_kernel<<<dim3(Bb), 256, 0, stream>>>(bounds, view_p, ws);
        dim3 grid(Nn / 64, Bb);
        calib_kernel<<<grid, 256, 0, stream>>>(pc, mask, bounds, inv_param,
                                               proj_fine, proj_finez, view_p,
                                               ws, out);
    } else {
        dim3 grid(Nn / 64, Bb);
        calib_fallback<<<grid, 256, 0, stream>>>(pc, mask, bounds, inv_param,
                                                 proj_fine, proj_finez, view_p,
                                                 out);
    }
}

// Round 5
// 29.749 us; speedup vs baseline: 1.4057x; 1.4057x over previous
//
#include <hip/hip_runtime.h>
#include <math.h>

constexpr int IMG = 224;
constexpr int Bb  = 16;
constexpr int Vv  = 8;
constexpr int Nn  = 8192;
constexpr int Mm  = 1024;
constexpr int G   = 16;                 // bins per axis
constexpr float Hh = 1.0f / 16.0f;      // cell size, normalized coords

// ws layout: entries float4[Bb][Mm]  (256 KiB)  |  starts int[Bb][260]

// ---------- Kernel A: bin candidates into a 16x16 grid --------------------
__global__ __launch_bounds__(256) void prep_kernel(
    const float* __restrict__ bounds, const int* __restrict__ view_p,
    float4* __restrict__ ws_e, int* __restrict__ ws_s)
{
    const int view = *view_p;
    const int b = blockIdx.x;
    const int t = threadIdx.x;
    __shared__ int s_cnt[256];
    __shared__ int s_ps[256];
    __shared__ int s_cur[256];
    s_cnt[t] = 0;
    __syncthreads();

    const float* bnd = bounds + (size_t)(b * Vv + view) * Mm * 2;
    float bdx[4], bdy[4];
    int cell[4];
    #pragma unroll
    for (int u = 0; u < 4; ++u) {
        int j = t + 256 * u;
        float2 bxy = reinterpret_cast<const float2*>(bnd)[j];
        bdx[u] = bxy.x / (float)IMG;      // exact IEEE div, matches ref
        bdy[u] = bxy.y / (float)IMG;
        int cx = min(G - 1, max(0, (int)(bdx[u] * (float)G)));
        int cy = min(G - 1, max(0, (int)(bdy[u] * (float)G)));
        cell[u] = cy * G + cx;
        atomicAdd(&s_cnt[cell[u]], 1);
    }
    __syncthreads();

    // inclusive prefix sum (Hillis-Steele) over 256 cells
    s_ps[t] = s_cnt[t];
    __syncthreads();
    for (int s = 1; s < 256; s <<= 1) {
        int add = (t >= s) ? s_ps[t - s] : 0;
        __syncthreads();
        s_ps[t] += add;
        __syncthreads();
    }
    int start = s_ps[t] - s_cnt[t];       // exclusive
    s_cur[t] = start;
    ws_s[b * 260 + t] = start;
    if (t == 0) ws_s[b * 260 + 256] = Mm;
    __syncthreads();

    // scatter packed entries (order within a cell is atomic-arbitrary; the
    // lexicographic (d2, j) reduction makes the result order-invariant)
    #pragma unroll
    for (int u = 0; u < 4; ++u) {
        int j = t + 256 * u;
        int pos = atomicAdd(&s_cur[cell[u]], 1);
        float nrm = __fadd_rn(__fmul_rn(bdx[u], bdx[u]), __fmul_rn(bdy[u], bdy[u]));
        ws_e[(size_t)b * Mm + pos] = make_float4(bdx[u], bdy[u], nrm, __int_as_float(j));
    }
}

// ---------- Kernel B: grid-pruned NN + epilogue ---------------------------
__global__ __launch_bounds__(256) void calib_kernel(
    const float* __restrict__ pc,         // (B, N, 3)
    const float* __restrict__ mask,       // (B, V, IMG, IMG)
    const float* __restrict__ bounds,     // (B, V, M, 2)
    const float* __restrict__ inv_param,  // (B, V, 4, 4)
    const float* __restrict__ proj_fine,  // (B, V, N, 2)
    const float* __restrict__ proj_finez, // (B, V, N)
    const int*   __restrict__ view_p,
    const float4* __restrict__ ws_e,
    const int*   __restrict__ ws_s,
    float*       __restrict__ out)        // (B, N, 3)
{
    const int view = *view_p;
    const int b = blockIdx.y;
    const int t = threadIdx.x;
    const int i = blockIdx.x * 256 + t;

    __shared__ float4 s_e[Mm];
    __shared__ int s_start[257];
    const float4* we = ws_e + (size_t)b * Mm;
    #pragma unroll
    for (int u = 0; u < 4; ++u) s_e[t + 256 * u] = we[t + 256 * u];
    s_start[t] = ws_s[b * 260 + t];
    if (t == 0) s_start[256] = Mm;
    __syncthreads();

    const size_t pf = (size_t)(b * Vv + view) * Nn + i;
    float2 pxy = reinterpret_cast<const float2*>(proj_fine)[pf];

    int i0 = (int)rintf(pxy.x);                 // round half-to-even
    int i1 = (int)rintf((float)IMG - pxy.y);

    // padded-mask probe (decides whether the NN result is used at all)
    int xi = min(max(i1 + 1, 0), IMG + 1);
    int yi = min(max(i0 + 1, 0), IMG + 1);
    float mval = 0.0f;
    if (xi >= 1 && xi <= IMG && yi >= 1 && yi <= IMG)
        mval = mask[((size_t)(b * Vv + view) * IMG + (xi - 1)) * IMG + (yi - 1)];
    const bool use_back = (mval == 0.0f);

    float r0 = 0.0f, r1 = 0.0f, r2 = 0.0f;
    if (use_back) {
        float ox = (float)i0 / (float)IMG;
        float oy = (float)i1 / (float)IMG;
        float o2 = __fadd_rn(__fmul_rn(ox, ox), __fmul_rn(oy, oy));
        // exact power-of-2 scale; d2 bits identical to ref association
        float n2ox = __fmul_rn(-2.0f, ox);
        float n2oy = __fmul_rn(-2.0f, oy);

        int cx = min(G - 1, max(0, (int)(ox * (float)G)));
        int cy = min(G - 1, max(0, (int)(oy * (float)G)));

        float best = INFINITY;
        int   bj   = 0;
        for (int r = 0; r <= G; ++r) {
            if (r > 0) {
                // unvisited candidates (ring >= r) have computed d2 >=
                // ((r-1)*h)^2 - 2e-6; stop iff they can't win or tie.
                float lim = (float)(r - 1) * Hh;
                if (best < lim * lim - 1e-5f) break;
            }
            int x0 = max(0, cx - r), x1 = min(G - 1, cx + r);
            int y0 = max(0, cy - r), y1 = min(G - 1, cy + r);
            for (int yy = y0; yy <= y1; ++yy) {
                bool yedge = (yy == cy - r) || (yy == cy + r);
                for (int xx = x0; xx <= x1; ++xx) {
                    if (r > 0 && !yedge && xx != cx - r && xx != cx + r)
                        continue;                    // interior: already done
                    int c = yy * G + xx;
                    int e0 = s_start[c], e1 = s_start[c + 1];
                    for (int e = e0; e < e1; ++e) {
                        float4 cd = s_e[e];
                        float dn = __fadd_rn(__fmul_rn(n2ox, cd.x), __fmul_rn(n2oy, cd.y));
                        float d2 = __fadd_rn(__fadd_rn(o2, cd.z), dn);
                        int   j  = __float_as_int(cd.w);
                        bool better = (d2 < best) || (d2 == best && j < bj);
                        best = better ? d2 : best;
                        bj   = better ? j  : bj;
                    }
                }
            }
        }

        // back-projection: [nbx*z, nby*z, z, 1] @ inv_param[b, view][:, 0:3]
        const float* bnd = bounds + (size_t)(b * Vv + view) * Mm * 2;
        float nbx = bnd[2 * bj];
        float nby = bnd[2 * bj + 1];
        float z   = proj_finez[pf];
        const float* ip = inv_param + (size_t)(b * Vv + view) * 16;
        float h0 = nbx * z, h1 = nby * z;
        r0 = h0 * ip[0] + h1 * ip[4] + z * ip[8]  + ip[12];
        r1 = h0 * ip[1] + h1 * ip[5] + z * ip[9]  + ip[13];
        r2 = h0 * ip[2] + h1 * ip[6] + z * ip[10] + ip[14];
    }

    const size_t ob = ((size_t)b * Nn + i) * 3;
    float c0 = pc[ob], c1 = pc[ob + 1], c2 = pc[ob + 2];
    out[ob]     = use_back ? r0 : c0;
    out[ob + 1] = use_back ? r1 : c1;
    out[ob + 2] = use_back ? r2 : c2;
}

// ---------- Fallback: full scan (known-correct), if ws too small ----------
__global__ __launch_bounds__(256) void calib_fallback(
    const float* __restrict__ pc, const float* __restrict__ mask,
    const float* __restrict__ bounds, const float* __restrict__ inv_param,
    const float* __restrict__ proj_fine, const float* __restrict__ proj_finez,
    const int* __restrict__ view_p, float* __restrict__ out)
{
    const int view = *view_p;
    const int b = blockIdx.y;
    const int s = threadIdx.x & 3;
    const int p_local = threadIdx.x >> 2;
    const int i = blockIdx.x * 64 + p_local;

    __shared__ float4 s_bd[Mm];
    const float* bnd = bounds + (size_t)(b * Vv + view) * Mm * 2;
    for (int j = threadIdx.x; j < Mm; j += 256) {
        float2 bxy = reinterpret_cast<const float2*>(bnd)[j];
        float bdx = bxy.x / (float)IMG;
        float bdy = bxy.y / (float)IMG;
        float nrm = __fadd_rn(__fmul_rn(bdx, bdx), __fmul_rn(bdy, bdy));
        s_bd[j] = make_float4(bdx, bdy, nrm, 0.0f);
    }
    __syncthreads();

    const size_t pf = (size_t)(b * Vv + view) * Nn + i;
    float2 pxy = reinterpret_cast<const float2*>(proj_fine)[pf];
    int i0 = (int)rintf(pxy.x);
    int i1 = (int)rintf((float)IMG - pxy.y);
    float ox = (float)i0 / (float)IMG;
    float oy = (float)i1 / (float)IMG;
    float o2 = __fadd_rn(__fmul_rn(ox, ox), __fmul_rn(oy, oy));
    float n2ox = __fmul_rn(-2.0f, ox);
    float n2oy = __fmul_rn(-2.0f, oy);

    float best = INFINITY;
    int bj = 0;
    const float4* sp = s_bd + s;
    #pragma unroll 4
    for (int q = 0; q < Mm / 4; ++q) {
        float4 bd = sp[4 * q];
        int j = 4 * q + s;
        float dn = __fadd_rn(__fmul_rn(n2ox, bd.x), __fmul_rn(n2oy, bd.y));
        float d2 = __fadd_rn(__fadd_rn(o2, bd.z), dn);
        bool c = d2 < best;
        bj = c ? j : bj;
        best = fminf(best, d2);
    }
    #pragma unroll
    for (int off = 1; off < 4; off <<= 1) {
        float bo = __shfl_xor(best, off);
        int   jo = __shfl_xor(bj, off);
        bool  c  = (bo < best) || (bo == best && jo < bj);
        best = c ? bo : best;
        bj   = c ? jo : bj;
    }
    if (s == 0) {
        int xi = min(max(i1 + 1, 0), IMG + 1);
        int yi = min(max(i0 + 1, 0), IMG + 1);
        float mval = 0.0f;
        if (xi >= 1 && xi <= IMG && yi >= 1 && yi <= IMG)
            mval = mask[((size_t)(b * Vv + view) * IMG + (xi - 1)) * IMG + (yi - 1)];
        const bool use_back = (mval == 0.0f);
        float nbx = bnd[2 * bj];
        float nby = bnd[2 * bj + 1];
        float z   = proj_finez[pf];
        const float* ip = inv_param + (size_t)(b * Vv + view) * 16;
        float h0 = nbx * z, h1 = nby * z;
        float r0 = h0 * ip[0] + h1 * ip[4] + z * ip[8]  + ip[12];
        float r1 = h0 * ip[1] + h1 * ip[5] + z * ip[9]  + ip[13];
        float r2 = h0 * ip[2] + h1 * ip[6] + z * ip[10] + ip[14];
        const size_t ob = ((size_t)b * Nn + i) * 3;
        float c0 = pc[ob], c1 = pc[ob + 1], c2 = pc[ob + 2];
        out[ob]     = use_back ? r0 : c0;
        out[ob + 1] = use_back ? r1 : c1;
        out[ob + 2] = use_back ? r2 : c2;
    }
}

extern "C" void kernel_launch(void* const* d_in, const int* in_sizes, int n_in,
                              void* d_out, int out_size, void* d_ws, size_t ws_size,
                              hipStream_t stream) {
    const float* pc         = (const float*)d_in[0];
    const float* mask       = (const float*)d_in[1];
    const float* bounds     = (const float*)d_in[2];
    const float* inv_param  = (const float*)d_in[3];
    const float* proj_fine  = (const float*)d_in[4];
    const float* proj_finez = (const float*)d_in[5];
    const int*   view_p     = (const int*)d_in[6];
    float* out = (float*)d_out;

    const size_t ws_need = (size_t)Bb * Mm * sizeof(float4)
                         + (size_t)Bb * 260 * sizeof(int);
    if (ws_size >= ws_need) {
        float4* ws_e = (float4*)d_ws;
        int*    ws_s = (int*)((char*)d_ws + (size_t)Bb * Mm * sizeof(float4));
        prep_kernel<<<dim3(Bb), 256, 0, stream>>>(bounds, view_p, ws_e, ws_s);
        dim3 grid(Nn / 256, Bb);
        calib_kernel<<<grid, 256, 0, stream>>>(pc, mask, bounds, inv_param,
                                               proj_fine, proj_finez, view_p,
                                               ws_e, ws_s, out);
    } else {
        dim3 grid(Nn / 64, Bb);
        calib_fallback<<<grid, 256, 0, stream>>>(pc, mask, bounds, inv_param,
                                                 proj_fine, proj_finez, view_p,
                                                 out);
    }
}

// Round 6
// 28.536 us; speedup vs baseline: 1.4654x; 1.0425x over previous
//
#include <hip/hip_runtime.h>
#include <math.h>

constexpr int IMG = 224;
constexpr int Bb  = 16;
constexpr int Vv  = 8;
constexpr int Nn  = 8192;
constexpr int Mm  = 1024;
constexpr int G   = 16;                 // bins per axis
constexpr float Hh = 1.0f / 16.0f;      // cell size, normalized coords

// ws layout: entries float4[Bb][Mm]  (256 KiB)  |  starts int[Bb][260]

// ---------- Kernel A: bin candidates into a 16x16 grid --------------------
__global__ __launch_bounds__(256) void prep_kernel(
    const float* __restrict__ bounds, const int* __restrict__ view_p,
    float4* __restrict__ ws_e, int* __restrict__ ws_s)
{
    const int view = *view_p;
    const int b = blockIdx.x;
    const int t = threadIdx.x;
    __shared__ int s_cnt[256];
    __shared__ int s_ps[256];
    __shared__ int s_cur[256];
    s_cnt[t] = 0;
    __syncthreads();

    const float* bnd = bounds + (size_t)(b * Vv + view) * Mm * 2;
    float bdx[4], bdy[4];
    int cell[4];
    #pragma unroll
    for (int u = 0; u < 4; ++u) {
        int j = t + 256 * u;
        float2 bxy = reinterpret_cast<const float2*>(bnd)[j];
        bdx[u] = bxy.x / (float)IMG;      // exact IEEE div, matches ref
        bdy[u] = bxy.y / (float)IMG;
        int cx = min(G - 1, max(0, (int)(bdx[u] * (float)G)));
        int cy = min(G - 1, max(0, (int)(bdy[u] * (float)G)));
        cell[u] = cy * G + cx;
        atomicAdd(&s_cnt[cell[u]], 1);
    }
    __syncthreads();

    // inclusive prefix sum (Hillis-Steele) over 256 cells
    s_ps[t] = s_cnt[t];
    __syncthreads();
    for (int s = 1; s < 256; s <<= 1) {
        int add = (t >= s) ? s_ps[t - s] : 0;
        __syncthreads();
        s_ps[t] += add;
        __syncthreads();
    }
    int start = s_ps[t] - s_cnt[t];       // exclusive
    s_cur[t] = start;
    ws_s[b * 260 + t] = start;
    if (t == 0) ws_s[b * 260 + 256] = Mm;
    __syncthreads();

    // scatter packed entries (order within a cell is atomic-arbitrary; the
    // lexicographic (d2, j) reduction makes the result order-invariant)
    #pragma unroll
    for (int u = 0; u < 4; ++u) {
        int j = t + 256 * u;
        int pos = atomicAdd(&s_cur[cell[u]], 1);
        float nrm = __fadd_rn(__fmul_rn(bdx[u], bdx[u]), __fmul_rn(bdy[u], bdy[u]));
        ws_e[(size_t)b * Mm + pos] = make_float4(bdx[u], bdy[u], nrm, __int_as_float(j));
    }
}

// ---------- Kernel B: grid-pruned NN, 4 lanes/point -----------------------
// Block = 256 threads = 64 points x 4 lanes. Lane s scans 3x3 cells k===s mod 4.
__global__ __launch_bounds__(256) void calib_kernel(
    const float* __restrict__ pc,         // (B, N, 3)
    const float* __restrict__ mask,       // (B, V, IMG, IMG)
    const float* __restrict__ bounds,     // (B, V, M, 2)
    const float* __restrict__ inv_param,  // (B, V, 4, 4)
    const float* __restrict__ proj_fine,  // (B, V, N, 2)
    const float* __restrict__ proj_finez, // (B, V, N)
    const int*   __restrict__ view_p,
    const float4* __restrict__ ws_e,
    const int*   __restrict__ ws_s,
    float*       __restrict__ out)        // (B, N, 3)
{
    const int view = *view_p;
    const int b = blockIdx.y;
    const int t = threadIdx.x;
    const int s = t & 3;
    const int p = t >> 2;
    const int i = blockIdx.x * 64 + p;

    __shared__ float4 s_e[Mm];
    __shared__ int s_start[257];
    const float4* we = ws_e + (size_t)b * Mm;
    #pragma unroll
    for (int u = 0; u < 4; ++u) s_e[t + 256 * u] = we[t + 256 * u];
    s_start[t] = ws_s[b * 260 + t];
    if (t == 0) s_start[256] = Mm;
    __syncthreads();

    const size_t pf = (size_t)(b * Vv + view) * Nn + i;
    float2 pxy = reinterpret_cast<const float2*>(proj_fine)[pf];

    int i0 = (int)rintf(pxy.x);                 // round half-to-even
    int i1 = (int)rintf((float)IMG - pxy.y);

    // padded-mask probe (same address for the 4 lanes of a point)
    int xi = min(max(i1 + 1, 0), IMG + 1);
    int yi = min(max(i0 + 1, 0), IMG + 1);
    float mval = 0.0f;
    if (xi >= 1 && xi <= IMG && yi >= 1 && yi <= IMG)
        mval = mask[((size_t)(b * Vv + view) * IMG + (xi - 1)) * IMG + (yi - 1)];
    const bool use_back = (mval == 0.0f);

    if (use_back) {
        float ox = (float)i0 / (float)IMG;
        float oy = (float)i1 / (float)IMG;
        float o2 = __fadd_rn(__fmul_rn(ox, ox), __fmul_rn(oy, oy));
        // exact power-of-2 scale; d2 bits identical to ref association
        float n2ox = __fmul_rn(-2.0f, ox);
        float n2oy = __fmul_rn(-2.0f, oy);

        int cx = min(G - 1, max(0, (int)(ox * (float)G)));
        int cy = min(G - 1, max(0, (int)(oy * (float)G)));

        float best = INFINITY;
        int   bj   = 0;

        // fast path: rings 0..1 (3x3 block), cells split across 4 lanes
        #pragma unroll
        for (int k = 0; k < 9; ++k) {
            if ((k & 3) != s) continue;          // compile-time per-lane set
            int yy = cy + k / 3 - 1;
            int xx = cx + k % 3 - 1;
            if (yy >= 0 && yy < G && xx >= 0 && xx < G) {
                int c = yy * G + xx;
                int e0 = s_start[c], e1 = s_start[c + 1];
                for (int e = e0; e < e1; ++e) {
                    float4 cd = s_e[e];
                    float dn = __fadd_rn(__fmul_rn(n2ox, cd.x), __fmul_rn(n2oy, cd.y));
                    float d2 = __fadd_rn(__fadd_rn(o2, cd.z), dn);
                    int   j  = __float_as_int(cd.w);
                    bool better = (d2 < best) || (d2 == best && j < bj);
                    best = better ? d2 : best;
                    bj   = better ? j  : bj;
                }
            }
        }

        // merge the 4 lanes (xor 1,2 stays within the 4-lane group)
        #pragma unroll
        for (int off = 1; off < 4; off <<= 1) {
            float bo = __shfl_xor(best, off);
            int   jo = __shfl_xor(bj, off);
            bool  c  = (bo < best) || (bo == best && jo < bj);
            best = c ? bo : best;
            bj   = c ? jo : bj;
        }

        // slow path (P ~ 3e-6): unvisited rings >=2 have d2 >= h^2 - 2e-6
        if (!(best < Hh * Hh - 1e-5f) && s == 0) {
            for (int r = 2; r <= G; ++r) {
                float lim = (float)(r - 1) * Hh;
                if (best < lim * lim - 1e-5f) break;
                int x0 = max(0, cx - r), x1 = min(G - 1, cx + r);
                int y0 = max(0, cy - r), y1 = min(G - 1, cy + r);
                for (int yy = y0; yy <= y1; ++yy) {
                    bool yedge = (yy == cy - r) || (yy == cy + r);
                    for (int xx = x0; xx <= x1; ++xx) {
                        if (!yedge && xx != cx - r && xx != cx + r) continue;
                        int c = yy * G + xx;
                        int e0 = s_start[c], e1 = s_start[c + 1];
                        for (int e = e0; e < e1; ++e) {
                            float4 cd = s_e[e];
                            float dn = __fadd_rn(__fmul_rn(n2ox, cd.x), __fmul_rn(n2oy, cd.y));
                            float d2 = __fadd_rn(__fadd_rn(o2, cd.z), dn);
                            int   j  = __float_as_int(cd.w);
                            bool better = (d2 < best) || (d2 == best && j < bj);
                            best = better ? d2 : best;
                            bj   = better ? j  : bj;
                        }
                    }
                }
            }
        }

        if (s == 0) {
            // back-projection: [nbx*z, nby*z, z, 1] @ inv_param[:, 0:3]
            const float* bnd = bounds + (size_t)(b * Vv + view) * Mm * 2;
            float nbx = bnd[2 * bj];
            float nby = bnd[2 * bj + 1];
            float z   = proj_finez[pf];
            const float* ip = inv_param + (size_t)(b * Vv + view) * 16;
            float h0 = nbx * z, h1 = nby * z;
            float r0 = h0 * ip[0] + h1 * ip[4] + z * ip[8]  + ip[12];
            float r1 = h0 * ip[1] + h1 * ip[5] + z * ip[9]  + ip[13];
            float r2 = h0 * ip[2] + h1 * ip[6] + z * ip[10] + ip[14];
            const size_t ob = ((size_t)b * Nn + i) * 3;
            out[ob]     = r0;
            out[ob + 1] = r1;
            out[ob + 2] = r2;
        }
    } else if (s == 0) {
        const size_t ob = ((size_t)b * Nn + i) * 3;
        out[ob]     = pc[ob];
        out[ob + 1] = pc[ob + 1];
        out[ob + 2] = pc[ob + 2];
    }
}

// ---------- Fallback: full scan (known-correct), if ws too small ----------
__global__ __launch_bounds__(256) void calib_fallback(
    const float* __restrict__ pc, const float* __restrict__ mask,
    const float* __restrict__ bounds, const float* __restrict__ inv_param,
    const float* __restrict__ proj_fine, const float* __restrict__ proj_finez,
    const int* __restrict__ view_p, float* __restrict__ out)
{
    const int view = *view_p;
    const int b = blockIdx.y;
    const int s = threadIdx.x & 3;
    const int p_local = threadIdx.x >> 2;
    const int i = blockIdx.x * 64 + p_local;

    __shared__ float4 s_bd[Mm];
    const float* bnd = bounds + (size_t)(b * Vv + view) * Mm * 2;
    for (int j = threadIdx.x; j < Mm; j += 256) {
        float2 bxy = reinterpret_cast<const float2*>(bnd)[j];
        float bdx = bxy.x / (float)IMG;
        float bdy = bxy.y / (float)IMG;
        float nrm = __fadd_rn(__fmul_rn(bdx, bdx), __fmul_rn(bdy, bdy));
        s_bd[j] = make_float4(bdx, bdy, nrm, 0.0f);
    }
    __syncthreads();

    const size_t pf = (size_t)(b * Vv + view) * Nn + i;
    float2 pxy = reinterpret_cast<const float2*>(proj_fine)[pf];
    int i0 = (int)rintf(pxy.x);
    int i1 = (int)rintf((float)IMG - pxy.y);
    float ox = (float)i0 / (float)IMG;
    float oy = (float)i1 / (float)IMG;
    float o2 = __fadd_rn(__fmul_rn(ox, ox), __fmul_rn(oy, oy));
    float n2ox = __fmul_rn(-2.0f, ox);
    float n2oy = __fmul_rn(-2.0f, oy);

    float best = INFINITY;
    int bj = 0;
    const float4* sp = s_bd + s;
    #pragma unroll 4
    for (int q = 0; q < Mm / 4; ++q) {
        float4 bd = sp[4 * q];
        int j = 4 * q + s;
        float dn = __fadd_rn(__fmul_rn(n2ox, bd.x), __fmul_rn(n2oy, bd.y));
        float d2 = __fadd_rn(__fadd_rn(o2, bd.z), dn);
        bool c = d2 < best;
        bj = c ? j : bj;
        best = fminf(best, d2);
    }
    #pragma unroll
    for (int off = 1; off < 4; off <<= 1) {
        float bo = __shfl_xor(best, off);
        int   jo = __shfl_xor(bj, off);
        bool  c  = (bo < best) || (bo == best && jo < bj);
        best = c ? bo : best;
        bj   = c ? jo : bj;
    }
    if (s == 0) {
        int xi = min(max(i1 + 1, 0), IMG + 1);
        int yi = min(max(i0 + 1, 0), IMG + 1);
        float mval = 0.0f;
        if (xi >= 1 && xi <= IMG && yi >= 1 && yi <= IMG)
            mval = mask[((size_t)(b * Vv + view) * IMG + (xi - 1)) * IMG + (yi - 1)];
        const bool use_back = (mval == 0.0f);
        float nbx = bnd[2 * bj];
        float nby = bnd[2 * bj + 1];
        float z   = proj_finez[pf];
        const float* ip = inv_param + (size_t)(b * Vv + view) * 16;
        float h0 = nbx * z, h1 = nby * z;
        float r0 = h0 * ip[0] + h1 * ip[4] + z * ip[8]  + ip[12];
        float r1 = h0 * ip[1] + h1 * ip[5] + z * ip[9]  + ip[13];
        float r2 = h0 * ip[2] + h1 * ip[6] + z * ip[10] + ip[14];
        const size_t ob = ((size_t)b * Nn + i) * 3;
        float c0 = pc[ob], c1 = pc[ob + 1], c2 = pc[ob + 2];
        out[ob]     = use_back ? r0 : c0;
        out[ob + 1] = use_back ? r1 : c1;
        out[ob + 2] = use_back ? r2 : c2;
    }
}

extern "C" void kernel_launch(void* const* d_in, const int* in_sizes, int n_in,
                              void* d_out, int out_size, void* d_ws, size_t ws_size,
                              hipStream_t stream) {
    const float* pc         = (const float*)d_in[0];
    const float* mask       = (const float*)d_in[1];
    const float* bounds     = (const float*)d_in[2];
    const float* inv_param  = (const float*)d_in[3];
    const float* proj_fine  = (const float*)d_in[4];
    const float* proj_finez = (const float*)d_in[5];
    const int*   view_p     = (const int*)d_in[6];
    float* out = (float*)d_out;

    const size_t ws_need = (size_t)Bb * Mm * sizeof(float4)
                         + (size_t)Bb * 260 * sizeof(int);
    if (ws_size >= ws_need) {
        float4* ws_e = (float4*)d_ws;
        int*    ws_s = (int*)((char*)d_ws + (size_t)Bb * Mm * sizeof(float4));
        prep_kernel<<<dim3(Bb), 256, 0, stream>>>(bounds, view_p, ws_e, ws_s);
        dim3 grid(Nn / 64, Bb);
        calib_kernel<<<grid, 256, 0, stream>>>(pc, mask, bounds, inv_param,
                                               proj_fine, proj_finez, view_p,
                                               ws_e, ws_s, out);
    } else {
        dim3 grid(Nn / 64, Bb);
        calib_fallback<<<grid, 256, 0, stream>>>(pc, mask, bounds, inv_param,
                                                 proj_fine, proj_finez, view_p,
                                                 out);
    }
}

// Round 7
// 22.075 us; speedup vs baseline: 1.8943x; 1.2927x over previous
//
#include <hip/hip_runtime.h>
#include <math.h>

constexpr int IMG = 224;
constexpr int Bb  = 16;
constexpr int Vv  = 8;
constexpr int Nn  = 8192;
constexpr int Mm  = 1024;
constexpr int G   = 32;                 // bins per axis
constexpr float Hh = 1.0f / 32.0f;      // cell size, normalized coords

// ws layout: entries float4[Bb][Mm] (256 KiB) | starts ushort[Bb][1040]

// ---------- Kernel A: bin candidates into a 32x32 grid --------------------
__global__ __launch_bounds__(256) void prep_kernel(
    const float* __restrict__ bounds, const int* __restrict__ view_p,
    float4* __restrict__ ws_e, unsigned short* __restrict__ ws_s)
{
    const int view = *view_p;
    const int b = blockIdx.x;
    const int t = threadIdx.x;
    __shared__ int s_cnt[1024];
    __shared__ int s_cur[1024];
    __shared__ int s_part[256];
    #pragma unroll
    for (int u = 0; u < 4; ++u) s_cnt[t + 256 * u] = 0;
    __syncthreads();

    const float* bnd = bounds + (size_t)(b * Vv + view) * Mm * 2;
    float bdx[4], bdy[4];
    int cell[4];
    #pragma unroll
    for (int u = 0; u < 4; ++u) {
        int j = t + 256 * u;
        float2 bxy = reinterpret_cast<const float2*>(bnd)[j];
        bdx[u] = bxy.x / (float)IMG;      // exact IEEE div, matches ref
        bdy[u] = bxy.y / (float)IMG;
        int cx = min(G - 1, max(0, (int)(bdx[u] * (float)G)));
        int cy = min(G - 1, max(0, (int)(bdy[u] * (float)G)));
        cell[u] = cy * G + cx;
        atomicAdd(&s_cnt[cell[u]], 1);
    }
    __syncthreads();

    // prefix sum over 1024 cells: 4 serial per thread + Hillis-Steele on 256
    int c0 = s_cnt[4 * t], c1 = s_cnt[4 * t + 1];
    int c2 = s_cnt[4 * t + 2], c3 = s_cnt[4 * t + 3];
    int psum = c0 + c1 + c2 + c3;
    s_part[t] = psum;
    __syncthreads();
    for (int sh = 1; sh < 256; sh <<= 1) {
        int add = (t >= sh) ? s_part[t - sh] : 0;
        __syncthreads();
        s_part[t] += add;
        __syncthreads();
    }
    int base = s_part[t] - psum;          // exclusive over cell group 4t..
    int st0 = base, st1 = base + c0, st2 = base + c0 + c1, st3 = base + c0 + c1 + c2;
    unsigned short* wss = ws_s + b * 1040;
    wss[4 * t]     = (unsigned short)st0;
    wss[4 * t + 1] = (unsigned short)st1;
    wss[4 * t + 2] = (unsigned short)st2;
    wss[4 * t + 3] = (unsigned short)st3;
    if (t == 0) wss[1024] = (unsigned short)Mm;
    s_cur[4 * t] = st0; s_cur[4 * t + 1] = st1;
    s_cur[4 * t + 2] = st2; s_cur[4 * t + 3] = st3;
    __syncthreads();

    // scatter packed entries (intra-cell order atomic-arbitrary; lex (d2,j)
    // reduction makes the final result order-invariant)
    #pragma unroll
    for (int u = 0; u < 4; ++u) {
        int j = t + 256 * u;
        int pos = atomicAdd(&s_cur[cell[u]], 1);
        float nrm = __fadd_rn(__fmul_rn(bdx[u], bdx[u]), __fmul_rn(bdy[u], bdy[u]));
        ws_e[(size_t)b * Mm + pos] = make_float4(bdx[u], bdy[u], nrm, __int_as_float(j));
    }
}

// ---------- Kernel B: grid-pruned NN, 4 lanes/point, tiered rings ---------
__global__ __launch_bounds__(256, 8) void calib_kernel(
    const float* __restrict__ pc,         // (B, N, 3)
    const float* __restrict__ mask,       // (B, V, IMG, IMG)
    const float* __restrict__ bounds,     // (B, V, M, 2)
    const float* __restrict__ inv_param,  // (B, V, 4, 4)
    const float* __restrict__ proj_fine,  // (B, V, N, 2)
    const float* __restrict__ proj_finez, // (B, V, N)
    const int*   __restrict__ view_p,
    const float4* __restrict__ ws_e,
    const unsigned short* __restrict__ ws_s,
    float*       __restrict__ out)        // (B, N, 3)
{
    const int view = *view_p;
    const int b = blockIdx.y;
    const int t = threadIdx.x;
    const int s = t & 3;
    const int p = t >> 2;
    const int i = blockIdx.x * 64 + p;

    __shared__ float4 s_e[Mm];
    __shared__ unsigned short s_start[1032];
    const float4* we = ws_e + (size_t)b * Mm;
    #pragma unroll
    for (int u = 0; u < 4; ++u) s_e[t + 256 * u] = we[t + 256 * u];
    const unsigned short* wss = ws_s + b * 1040;
    for (int c = t; c < 1025; c += 256) s_start[c] = wss[c];
    __syncthreads();

    const size_t pf = (size_t)(b * Vv + view) * Nn + i;
    float2 pxy = reinterpret_cast<const float2*>(proj_fine)[pf];

    int i0 = (int)rintf(pxy.x);                 // round half-to-even
    int i1 = (int)rintf((float)IMG - pxy.y);

    // padded-mask probe
    int xi = min(max(i1 + 1, 0), IMG + 1);
    int yi = min(max(i0 + 1, 0), IMG + 1);
    float mval = 0.0f;
    if (xi >= 1 && xi <= IMG && yi >= 1 && yi <= IMG)
        mval = mask[((size_t)(b * Vv + view) * IMG + (xi - 1)) * IMG + (yi - 1)];
    const bool use_back = (mval == 0.0f);

    if (use_back) {
        float ox = (float)i0 / (float)IMG;
        float oy = (float)i1 / (float)IMG;
        float o2 = __fadd_rn(__fmul_rn(ox, ox), __fmul_rn(oy, oy));
        // exact power-of-2 scale; d2 bits identical to ref association
        float n2ox = __fmul_rn(-2.0f, ox);
        float n2oy = __fmul_rn(-2.0f, oy);

        int cx = min(G - 1, max(0, (int)(ox * (float)G)));
        int cy = min(G - 1, max(0, (int)(oy * (float)G)));

        float best = INFINITY;
        int   bj   = 0;

        // ---- tier 1: 3x3 block as 3 contiguous ranges, flattened --------
        int x0 = max(cx - 1, 0), x1 = min(cx + 1, G - 1);
        int b0 = 0, b1 = 0, b2 = 0, L0 = 0, L1 = 0, L2 = 0;
        if (cy - 1 >= 0) {
            int r = (cy - 1) * G;
            b0 = s_start[r + x0]; L0 = s_start[r + x1 + 1] - b0;
        }
        {
            int r = cy * G;
            b1 = s_start[r + x0]; L1 = s_start[r + x1 + 1] - b1;
        }
        if (cy + 1 < G) {
            int r = (cy + 1) * G;
            b2 = s_start[r + x0]; L2 = s_start[r + x1 + 1] - b2;
        }
        int L01 = L0 + L1;
        int T = L01 + L2;
        for (int u = s; u < T; u += 4) {
            bool inR1 = (u >= L0), inR2 = (u >= L01);
            int base = inR2 ? b2 : (inR1 ? b1 : b0);
            int off  = inR2 ? L01 : (inR1 ? L0 : 0);
            float4 cd = s_e[base + (u - off)];
            float dn = __fadd_rn(__fmul_rn(n2ox, cd.x), __fmul_rn(n2oy, cd.y));
            float d2 = __fadd_rn(__fadd_rn(o2, cd.z), dn);
            int   j  = __float_as_int(cd.w);
            bool better = (d2 < best) || (d2 == best && j < bj);
            best = better ? d2 : best;
            bj   = better ? j  : bj;
        }
        #pragma unroll
        for (int off = 1; off < 4; off <<= 1) {
            float bo = __shfl_xor(best, off);
            int   jo = __shfl_xor(bj, off);
            bool  c  = (bo < best) || (bo == best && jo < bj);
            best = c ? bo : best;
            bj   = c ? jo : bj;
        }

        // ---- tier 2 (P~4%): ring 2 (16 border cells), lane-parallel -----
        // unvisited after tier1 = Chebyshev ring>=2 => computed d2 >= h^2-2e-6
        if (!(best < Hh * Hh - 1e-5f)) {
            for (int k = s; k < 16; k += 4) {
                int xx, yy;
                if (k < 5)       { xx = cx - 2 + k;        yy = cy - 2; }
                else if (k < 10) { xx = cx - 2 + (k - 5);  yy = cy + 2; }
                else if (k < 13) { xx = cx - 2;            yy = cy - 1 + (k - 10); }
                else             { xx = cx + 2;            yy = cy - 1 + (k - 13); }
                if (xx >= 0 && xx < G && yy >= 0 && yy < G) {
                    int c = yy * G + xx;
                    int e0 = s_start[c], e1 = s_start[c + 1];
                    for (int e = e0; e < e1; ++e) {
                        float4 cd = s_e[e];
                        float dn = __fadd_rn(__fmul_rn(n2ox, cd.x), __fmul_rn(n2oy, cd.y));
                        float d2 = __fadd_rn(__fadd_rn(o2, cd.z), dn);
                        int   j  = __float_as_int(cd.w);
                        bool better = (d2 < best) || (d2 == best && j < bj);
                        best = better ? d2 : best;
                        bj   = better ? j  : bj;
                    }
                }
            }
            #pragma unroll
            for (int off = 1; off < 4; off <<= 1) {
                float bo = __shfl_xor(best, off);
                int   jo = __shfl_xor(bj, off);
                bool  c  = (bo < best) || (bo == best && jo < bj);
                best = c ? bo : best;
                bj   = c ? jo : bj;
            }

            // ---- tier 3 (P~4e-6): serial ring walker, rings >= 3 --------
            if (!(best < 4.0f * Hh * Hh - 1e-5f) && s == 0) {
                for (int r = 3; r <= G; ++r) {
                    float lim = (float)(r - 1) * Hh;
                    if (best < lim * lim - 1e-5f) break;
                    int rx0 = max(0, cx - r), rx1 = min(G - 1, cx + r);
                    int ry0 = max(0, cy - r), ry1 = min(G - 1, cy + r);
                    for (int yy = ry0; yy <= ry1; ++yy) {
                        bool yedge = (yy == cy - r) || (yy == cy + r);
                        for (int xx = rx0; xx <= rx1; ++xx) {
                            if (!yedge && xx != cx - r && xx != cx + r) continue;
                            int c = yy * G + xx;
                            int e0 = s_start[c], e1 = s_start[c + 1];
                            for (int e = e0; e < e1; ++e) {
                                float4 cd = s_e[e];
                                float dn = __fadd_rn(__fmul_rn(n2ox, cd.x), __fmul_rn(n2oy, cd.y));
                                float d2 = __fadd_rn(__fadd_rn(o2, cd.z), dn);
                                int   j  = __float_as_int(cd.w);
                                bool better = (d2 < best) || (d2 == best && j < bj);
                                best = better ? d2 : best;
                                bj   = better ? j  : bj;
                            }
                        }
                    }
                }
            }
        }

        if (s == 0) {
            // back-projection: [nbx*z, nby*z, z, 1] @ inv_param[:, 0:3]
            const float* bnd = bounds + (size_t)(b * Vv + view) * Mm * 2;
            float nbx = bnd[2 * bj];
            float nby = bnd[2 * bj + 1];
            float z   = proj_finez[pf];
            const float* ip = inv_param + (size_t)(b * Vv + view) * 16;
            float h0 = nbx * z, h1 = nby * z;
            float r0 = h0 * ip[0] + h1 * ip[4] + z * ip[8]  + ip[12];
            float r1 = h0 * ip[1] + h1 * ip[5] + z * ip[9]  + ip[13];
            float r2 = h0 * ip[2] + h1 * ip[6] + z * ip[10] + ip[14];
            const size_t ob = ((size_t)b * Nn + i) * 3;
            out[ob]     = r0;
            out[ob + 1] = r1;
            out[ob + 2] = r2;
        }
    } else if (s == 0) {
        const size_t ob = ((size_t)b * Nn + i) * 3;
        out[ob]     = pc[ob];
        out[ob + 1] = pc[ob + 1];
        out[ob + 2] = pc[ob + 2];
    }
}

// ---------- Fallback: full scan (known-correct), if ws too small ----------
__global__ __launch_bounds__(256) void calib_fallback(
    const float* __restrict__ pc, const float* __restrict__ mask,
    const float* __restrict__ bounds, const float* __restrict__ inv_param,
    const float* __restrict__ proj_fine, const float* __restrict__ proj_finez,
    const int* __restrict__ view_p, float* __restrict__ out)
{
    const int view = *view_p;
    const int b = blockIdx.y;
    const int s = threadIdx.x & 3;
    const int p_local = threadIdx.x >> 2;
    const int i = blockIdx.x * 64 + p_local;

    __shared__ float4 s_bd[Mm];
    const float* bnd = bounds + (size_t)(b * Vv + view) * Mm * 2;
    for (int j = threadIdx.x; j < Mm; j += 256) {
        float2 bxy = reinterpret_cast<const float2*>(bnd)[j];
        float bdx = bxy.x / (float)IMG;
        float bdy = bxy.y / (float)IMG;
        float nrm = __fadd_rn(__fmul_rn(bdx, bdx), __fmul_rn(bdy, bdy));
        s_bd[j] = make_float4(bdx, bdy, nrm, 0.0f);
    }
    __syncthreads();

    const size_t pf = (size_t)(b * Vv + view) * Nn + i;
    float2 pxy = reinterpret_cast<const float2*>(proj_fine)[pf];
    int i0 = (int)rintf(pxy.x);
    int i1 = (int)rintf((float)IMG - pxy.y);
    float ox = (float)i0 / (float)IMG;
    float oy = (float)i1 / (float)IMG;
    float o2 = __fadd_rn(__fmul_rn(ox, ox), __fmul_rn(oy, oy));
    float n2ox = __fmul_rn(-2.0f, ox);
    float n2oy = __fmul_rn(-2.0f, oy);

    float best = INFINITY;
    int bj = 0;
    const float4* sp = s_bd + s;
    #pragma unroll 4
    for (int q = 0; q < Mm / 4; ++q) {
        float4 bd = sp[4 * q];
        int j = 4 * q + s;
        float dn = __fadd_rn(__fmul_rn(n2ox, bd.x), __fmul_rn(n2oy, bd.y));
        float d2 = __fadd_rn(__fadd_rn(o2, bd.z), dn);
        bool c = d2 < best;
        bj = c ? j : bj;
        best = fminf(best, d2);
    }
    #pragma unroll
    for (int off = 1; off < 4; off <<= 1) {
        float bo = __shfl_xor(best, off);
        int   jo = __shfl_xor(bj, off);
        bool  c  = (bo < best) || (bo == best && jo < bj);
        best = c ? bo : best;
        bj   = c ? jo : bj;
    }
    if (s == 0) {
        int xi = min(max(i1 + 1, 0), IMG + 1);
        int yi = min(max(i0 + 1, 0), IMG + 1);
        float mval = 0.0f;
        if (xi >= 1 && xi <= IMG && yi >= 1 && yi <= IMG)
            mval = mask[((size_t)(b * Vv + view) * IMG + (xi - 1)) * IMG + (yi - 1)];
        const bool use_back = (mval == 0.0f);
        float nbx = bnd[2 * bj];
        float nby = bnd[2 * bj + 1];
        float z   = proj_finez[pf];
        const float* ip = inv_param + (size_t)(b * Vv + view) * 16;
        float h0 = nbx * z, h1 = nby * z;
        float r0 = h0 * ip[0] + h1 * ip[4] + z * ip[8]  + ip[12];
        float r1 = h0 * ip[1] + h1 * ip[5] + z * ip[9]  + ip[13];
        float r2 = h0 * ip[2] + h1 * ip[6] + z * ip[10] + ip[14];
        const size_t ob = ((size_t)b * Nn + i) * 3;
        float c0 = pc[ob], c1 = pc[ob + 1], c2 = pc[ob + 2];
        out[ob]     = use_back ? r0 : c0;
        out[ob + 1] = use_back ? r1 : c1;
        out[ob + 2] = use_back ? r2 : c2;
    }
}

extern "C" void kernel_launch(void* const* d_in, const int* in_sizes, int n_in,
                              void* d_out, int out_size, void* d_ws, size_t ws_size,
                              hipStream_t stream) {
    const float* pc         = (const float*)d_in[0];
    const float* mask       = (const float*)d_in[1];
    const float* bounds     = (const float*)d_in[2];
    const float* inv_param  = (const float*)d_in[3];
    const float* proj_fine  = (const float*)d_in[4];
    const float* proj_finez = (const float*)d_in[5];
    const int*   view_p     = (const int*)d_in[6];
    float* out = (float*)d_out;

    const size_t ws_need = (size_t)Bb * Mm * sizeof(float4)
                         + (size_t)Bb * 1040 * sizeof(unsigned short);
    if (ws_size >= ws_need) {
        float4* ws_e = (float4*)d_ws;
        unsigned short* ws_s =
            (unsigned short*)((char*)d_ws + (size_t)Bb * Mm * sizeof(float4));
        prep_kernel<<<dim3(Bb), 256, 0, stream>>>(bounds, view_p, ws_e, ws_s);
        dim3 grid(Nn / 64, Bb);
        calib_kernel<<<grid, 256, 0, stream>>>(pc, mask, bounds, inv_param,
                                               proj_fine, proj_finez, view_p,
                                               ws_e, ws_s, out);
    } else {
        dim3 grid(Nn / 64, Bb);
        calib_fallback<<<grid, 256, 0, stream>>>(pc, mask, bounds, inv_param,
                                                 proj_fine, proj_finez, view_p,
                                                 out);
    }
}

// Round 8
// 21.305 us; speedup vs baseline: 1.9628x; 1.0361x over previous
//
#include <hip/hip_runtime.h>
#include <math.h>

constexpr int IMG = 224;
constexpr int Bb  = 16;
constexpr int Vv  = 8;
constexpr int Nn  = 8192;
constexpr int Mm  = 1024;
constexpr int G   = 32;                 // bins per axis
constexpr float Hh = 1.0f / 32.0f;      // cell size, normalized coords

// ws layout: entries float4[Bb][Mm] (256 KiB) | starts ushort[Bb][1040]

// ---------- Kernel A: bin candidates into a 32x32 grid --------------------
__global__ __launch_bounds__(256) void prep_kernel(
    const float* __restrict__ bounds, const int* __restrict__ view_p,
    float4* __restrict__ ws_e, unsigned short* __restrict__ ws_s)
{
    const int view = *view_p;
    const int b = blockIdx.x;
    const int t = threadIdx.x;
    const int lane = t & 63;
    const int w = t >> 6;
    __shared__ int s_cnt[1024];           // counts, then reused as cursors
    __shared__ int s_wtot[4];
    #pragma unroll
    for (int u = 0; u < 4; ++u) s_cnt[t + 256 * u] = 0;
    __syncthreads();

    const float* bnd = bounds + (size_t)(b * Vv + view) * Mm * 2;
    float bdx[4], bdy[4];
    int cell[4];
    #pragma unroll
    for (int u = 0; u < 4; ++u) {
        int j = t + 256 * u;
        float2 bxy = reinterpret_cast<const float2*>(bnd)[j];
        bdx[u] = bxy.x / (float)IMG;      // exact IEEE div, matches ref
        bdy[u] = bxy.y / (float)IMG;
        int cx = min(G - 1, max(0, (int)(bdx[u] * (float)G)));
        int cy = min(G - 1, max(0, (int)(bdy[u] * (float)G)));
        cell[u] = cy * G + cx;
        atomicAdd(&s_cnt[cell[u]], 1);
    }
    __syncthreads();

    // prefix sum over 1024 cells: 4 serial/thread + wave shfl-scan + fixup
    int c0 = s_cnt[4 * t], c1 = s_cnt[4 * t + 1];
    int c2 = s_cnt[4 * t + 2], c3 = s_cnt[4 * t + 3];
    int psum = c0 + c1 + c2 + c3;
    int incl = psum;
    #pragma unroll
    for (int off = 1; off < 64; off <<= 1) {
        int v = __shfl_up(incl, off);
        if (lane >= off) incl += v;
    }
    if (lane == 63) s_wtot[w] = incl;
    __syncthreads();
    int basew = 0;
    for (int ww = 0; ww < w; ++ww) basew += s_wtot[ww];
    int base = basew + incl - psum;       // exclusive over cell group 4t..
    int st0 = base, st1 = base + c0, st2 = base + c0 + c1, st3 = base + c0 + c1 + c2;
    unsigned short* wss = ws_s + b * 1040;
    wss[4 * t]     = (unsigned short)st0;
    wss[4 * t + 1] = (unsigned short)st1;
    wss[4 * t + 2] = (unsigned short)st2;
    wss[4 * t + 3] = (unsigned short)st3;
    if (t == 0) wss[1024] = (unsigned short)Mm;
    s_cnt[4 * t] = st0; s_cnt[4 * t + 1] = st1;
    s_cnt[4 * t + 2] = st2; s_cnt[4 * t + 3] = st3;
    __syncthreads();

    // scatter packed entries (intra-cell order atomic-arbitrary; lex (d2,j)
    // reduction makes the final result order-invariant)
    #pragma unroll
    for (int u = 0; u < 4; ++u) {
        int j = t + 256 * u;
        int pos = atomicAdd(&s_cnt[cell[u]], 1);
        float nrm = __fadd_rn(__fmul_rn(bdx[u], bdx[u]), __fmul_rn(bdy[u], bdy[u]));
        ws_e[(size_t)b * Mm + pos] = make_float4(bdx[u], bdy[u], nrm, __int_as_float(j));
    }
}

// ---------- Kernel B: grid-pruned NN, 4 lanes/point, uniform 5x5 ----------
__global__ __launch_bounds__(256, 8) void calib_kernel(
    const float* __restrict__ pc,         // (B, N, 3)
    const float* __restrict__ mask,       // (B, V, IMG, IMG)
    const float* __restrict__ bounds,     // (B, V, M, 2)
    const float* __restrict__ inv_param,  // (B, V, 4, 4)
    const float* __restrict__ proj_fine,  // (B, V, N, 2)
    const float* __restrict__ proj_finez, // (B, V, N)
    const int*   __restrict__ view_p,
    const float4* __restrict__ ws_e,
    const unsigned short* __restrict__ ws_s,
    float*       __restrict__ out)        // (B, N, 3)
{
    const int view = *view_p;
    const int b = blockIdx.y;
    const int t = threadIdx.x;
    const int s = t & 3;
    const int p = t >> 2;
    const int i = blockIdx.x * 64 + p;

    __shared__ float4 s_e[Mm];
    __shared__ unsigned short s_start[1032];
    const float4* we = ws_e + (size_t)b * Mm;
    #pragma unroll
    for (int u = 0; u < 4; ++u) s_e[t + 256 * u] = we[t + 256 * u];
    const unsigned short* wss = ws_s + b * 1040;
    for (int c = t; c < 1025; c += 256) s_start[c] = wss[c];
    __syncthreads();

    const size_t pf = (size_t)(b * Vv + view) * Nn + i;
    float2 pxy = reinterpret_cast<const float2*>(proj_fine)[pf];

    int i0 = (int)rintf(pxy.x);                 // round half-to-even
    int i1 = (int)rintf((float)IMG - pxy.y);

    // padded-mask probe
    int xi = min(max(i1 + 1, 0), IMG + 1);
    int yi = min(max(i0 + 1, 0), IMG + 1);
    float mval = 0.0f;
    if (xi >= 1 && xi <= IMG && yi >= 1 && yi <= IMG)
        mval = mask[((size_t)(b * Vv + view) * IMG + (xi - 1)) * IMG + (yi - 1)];
    const bool use_back = (mval == 0.0f);

    if (use_back) {
        float ox = (float)i0 / (float)IMG;
        float oy = (float)i1 / (float)IMG;
        float o2 = __fadd_rn(__fmul_rn(ox, ox), __fmul_rn(oy, oy));
        // exact power-of-2 scale; d2 bits identical to prior rounds
        float n2ox = __fmul_rn(-2.0f, ox);
        float n2oy = __fmul_rn(-2.0f, oy);

        int cx = min(G - 1, max(0, (int)(ox * (float)G)));
        int cy = min(G - 1, max(0, (int)(oy * (float)G)));

        float best = INFINITY;
        int   bj   = 0;

        // ---- tier 1: full 5x5 window as 5 contiguous row-ranges ---------
        int x0 = max(cx - 2, 0), x1 = min(cx + 2, G - 1);
        int bases[5], offs[5];
        int T = 0;
        #pragma unroll
        for (int r = 0; r < 5; ++r) {
            int yy = cy - 2 + r;
            int bb = 0, LL = 0;
            if (yy >= 0 && yy < G) {
                int rowb = yy * G;
                bb = s_start[rowb + x0];
                LL = s_start[rowb + x1 + 1] - bb;
            }
            bases[r] = bb; offs[r] = T; T += LL;
        }
        for (int u = s; u < T; u += 4) {
            int base = bases[0], off = offs[0];
            #pragma unroll
            for (int r = 1; r < 5; ++r) {        // compile-time unrolled -> regs
                bool in = (u >= offs[r]);
                base = in ? bases[r] : base;
                off  = in ? offs[r]  : off;
            }
            float4 cd = s_e[base + (u - off)];
            float dn = __fadd_rn(__fmul_rn(n2ox, cd.x), __fmul_rn(n2oy, cd.y));
            float d2 = __fadd_rn(__fadd_rn(o2, cd.z), dn);
            int   j  = __float_as_int(cd.w);
            bool better = (d2 < best) || (d2 == best && j < bj);
            best = better ? d2 : best;
            bj   = better ? j  : bj;
        }
        #pragma unroll
        for (int off = 1; off < 4; off <<= 1) {
            float bo = __shfl_xor(best, off);
            int   jo = __shfl_xor(bj, off);
            bool  c  = (bo < best) || (bo == best && jo < bj);
            best = c ? bo : best;
            bj   = c ? jo : bj;
        }

        // ---- tier 2 (P~3e-6): serial ring walker, rings >= 3 ------------
        // unvisited = Chebyshev cell-ring >= 3 => d >= 2h => d2 >= 4h^2-slop
        if (!(best < 4.0f * Hh * Hh - 1e-5f) && s == 0) {
            for (int r = 3; r <= G; ++r) {
                float lim = (float)(r - 1) * Hh;
                if (best < lim * lim - 1e-5f) break;
                int rx0 = max(0, cx - r), rx1 = min(G - 1, cx + r);
                int ry0 = max(0, cy - r), ry1 = min(G - 1, cy + r);
                for (int yy = ry0; yy <= ry1; ++yy) {
                    bool yedge = (yy == cy - r) || (yy == cy + r);
                    for (int xx = rx0; xx <= rx1; ++xx) {
                        if (!yedge && xx != cx - r && xx != cx + r) continue;
                        int c = yy * G + xx;
                        int e0 = s_start[c], e1 = s_start[c + 1];
                        for (int e = e0; e < e1; ++e) {
                            float4 cd = s_e[e];
                            float dn = __fadd_rn(__fmul_rn(n2ox, cd.x), __fmul_rn(n2oy, cd.y));
                            float d2 = __fadd_rn(__fadd_rn(o2, cd.z), dn);
                            int   j  = __float_as_int(cd.w);
                            bool better = (d2 < best) || (d2 == best && j < bj);
                            best = better ? d2 : best;
                            bj   = better ? j  : bj;
                        }
                    }
                }
            }
        }

        if (s == 0) {
            // back-projection: [nbx*z, nby*z, z, 1] @ inv_param[:, 0:3]
            const float* bnd = bounds + (size_t)(b * Vv + view) * Mm * 2;
            float nbx = bnd[2 * bj];
            float nby = bnd[2 * bj + 1];
            float z   = proj_finez[pf];
            const float* ip = inv_param + (size_t)(b * Vv + view) * 16;
            float h0 = nbx * z, h1 = nby * z;
            float r0 = h0 * ip[0] + h1 * ip[4] + z * ip[8]  + ip[12];
            float r1 = h0 * ip[1] + h1 * ip[5] + z * ip[9]  + ip[13];
            float r2 = h0 * ip[2] + h1 * ip[6] + z * ip[10] + ip[14];
            const size_t ob = ((size_t)b * Nn + i) * 3;
            out[ob]     = r0;
            out[ob + 1] = r1;
            out[ob + 2] = r2;
        }
    } else if (s == 0) {
        const size_t ob = ((size_t)b * Nn + i) * 3;
        out[ob]     = pc[ob];
        out[ob + 1] = pc[ob + 1];
        out[ob + 2] = pc[ob + 2];
    }
}

// ---------- Fallback: full scan (known-correct), if ws too small ----------
__global__ __launch_bounds__(256) void calib_fallback(
    const float* __restrict__ pc, const float* __restrict__ mask,
    const float* __restrict__ bounds, const float* __restrict__ inv_param,
    const float* __restrict__ proj_fine, const float* __restrict__ proj_finez,
    const int* __restrict__ view_p, float* __restrict__ out)
{
    const int view = *view_p;
    const int b = blockIdx.y;
    const int s = threadIdx.x & 3;
    const int p_local = threadIdx.x >> 2;
    const int i = blockIdx.x * 64 + p_local;

    __shared__ float4 s_bd[Mm];
    const float* bnd = bounds + (size_t)(b * Vv + view) * Mm * 2;
    for (int j = threadIdx.x; j < Mm; j += 256) {
        float2 bxy = reinterpret_cast<const float2*>(bnd)[j];
        float bdx = bxy.x / (float)IMG;
        float bdy = bxy.y / (float)IMG;
        float nrm = __fadd_rn(__fmul_rn(bdx, bdx), __fmul_rn(bdy, bdy));
        s_bd[j] = make_float4(bdx, bdy, nrm, 0.0f);
    }
    __syncthreads();

    const size_t pf = (size_t)(b * Vv + view) * Nn + i;
    float2 pxy = reinterpret_cast<const float2*>(proj_fine)[pf];
    int i0 = (int)rintf(pxy.x);
    int i1 = (int)rintf((float)IMG - pxy.y);
    float ox = (float)i0 / (float)IMG;
    float oy = (float)i1 / (float)IMG;
    float o2 = __fadd_rn(__fmul_rn(ox, ox), __fmul_rn(oy, oy));
    float n2ox = __fmul_rn(-2.0f, ox);
    float n2oy = __fmul_rn(-2.0f, oy);

    float best = INFINITY;
    int bj = 0;
    const float4* sp = s_bd + s;
    #pragma unroll 4
    for (int q = 0; q < Mm / 4; ++q) {
        float4 bd = sp[4 * q];
        int j = 4 * q + s;
        float dn = __fadd_rn(__fmul_rn(n2ox, bd.x), __fmul_rn(n2oy, bd.y));
        float d2 = __fadd_rn(__fadd_rn(o2, bd.z), dn);
        bool c = d2 < best;
        bj = c ? j : bj;
        best = fminf(best, d2);
    }
    #pragma unroll
    for (int off = 1; off < 4; off <<= 1) {
        float bo = __shfl_xor(best, off);
        int   jo = __shfl_xor(bj, off);
        bool  c  = (bo < best) || (bo == best && jo < bj);
        best = c ? bo : best;
        bj   = c ? jo : bj;
    }
    if (s == 0) {
        int xi = min(max(i1 + 1, 0), IMG + 1);
        int yi = min(max(i0 + 1, 0), IMG + 1);
        float mval = 0.0f;
        if (xi >= 1 && xi <= IMG && yi >= 1 && yi <= IMG)
            mval = mask[((size_t)(b * Vv + view) * IMG + (xi - 1)) * IMG + (yi - 1)];
        const bool use_back = (mval == 0.0f);
        float nbx = bnd[2 * bj];
        float nby = bnd[2 * bj + 1];
        float z   = proj_finez[pf];
        const float* ip = inv_param + (size_t)(b * Vv + view) * 16;
        float h0 = nbx * z, h1 = nby * z;
        float r0 = h0 * ip[0] + h1 * ip[4] + z * ip[8]  + ip[12];
        float r1 = h0 * ip[1] + h1 * ip[5] + z * ip[9]  + ip[13];
        float r2 = h0 * ip[2] + h1 * ip[6] + z * ip[10] + ip[14];
        const size_t ob = ((size_t)b * Nn + i) * 3;
        float c0 = pc[ob], c1 = pc[ob + 1], c2 = pc[ob + 2];
        out[ob]     = use_back ? r0 : c0;
        out[ob + 1] = use_back ? r1 : c1;
        out[ob + 2] = use_back ? r2 : c2;
    }
}

extern "C" void kernel_launch(void* const* d_in, const int* in_sizes, int n_in,
                              void* d_out, int out_size, void* d_ws, size_t ws_size,
                              hipStream_t stream) {
    const float* pc         = (const float*)d_in[0];
    const float* mask       = (const float*)d_in[1];
    const float* bounds     = (const float*)d_in[2];
    const float* inv_param  = (const float*)d_in[3];
    const float* proj_fine  = (const float*)d_in[4];
    const float* proj_finez = (const float*)d_in[5];
    const int*   view_p     = (const int*)d_in[6];
    float* out = (float*)d_out;

    const size_t ws_need = (size_t)Bb * Mm * sizeof(float4)
                         + (size_t)Bb * 1040 * sizeof(unsigned short);
    if (ws_size >= ws_need) {
        float4* ws_e = (float4*)d_ws;
        unsigned short* ws_s =
            (unsigned short*)((char*)d_ws + (size_t)Bb * Mm * sizeof(float4));
        prep_kernel<<<dim3(Bb), 256, 0, stream>>>(bounds, view_p, ws_e, ws_s);
        dim3 grid(Nn / 64, Bb);
        calib_kernel<<<grid, 256, 0, stream>>>(pc, mask, bounds, inv_param,
                                               proj_fine, proj_finez, view_p,
                                               ws_e, ws_s, out);
    } else {
        dim3 grid(Nn / 64, Bb);
        calib_fallback<<<grid, 256, 0, stream>>>(pc, mask, bounds, inv_param,
                                                 proj_fine, proj_finez, view_p,
                                                 out);
    }
}